// Round 2
// baseline (501.170 us; speedup 1.0000x reference)
//
#include <hip/hip_runtime.h>
#include <stdint.h>

#define NT 256
#define SCAN_BLOCKS 2048
#define SAMPLE_BLOCKS 1024
#define MARGIN 5000u
#define HIST16_BINS 65536
#define HISTA_CAP 16384
#define B7_CAP 8192
#define TIE_CAP 512
#define UMASK 0x7fffffffu

// meta slots (zeroed each launch)
enum {
  M_LO = 0,    // lower bound of candidate band (u-space, inclusive)
  M_HI,        // upper bound (inclusive)
  M_BASE7,     // lo >> 7
  M_SPANA,     // number of (u>>7) bins in band
  M_NLESSLO,   // exact count of u < lo
  M_B7,        // selected u>>7 value (absolute)
  M_CUMA,      // candidates with (u>>7) < B7
  M_NB7,       // count of candidates with u>>7 == B7
  M_V,         // exact cutoff bit pattern
  M_ITHR,      // tie gets 1 iff idx >= I_thr
  M_FAIL,      // diagnostics only
  M_NMETA      // (padded to 64)
};

__global__ void k_zero(uint32_t* p, int n) {
  int i = blockIdx.x * NT + threadIdx.x;
  if (i < n) p[i] = 0;
}

// ---- Pass S: sample 2^20 elements (1024 chunks x 1024 contiguous), hist16 ----
__global__ void k_sample(const uint32_t* __restrict__ param, long long n,
                         uint32_t* __restrict__ hist16) {
  long long chunk = n / SAMPLE_BLOCKS;                 // 65536
  long long base = (long long)blockIdx.x * chunk;      // 16B-aligned
  const uint4* p4 = (const uint4*)(param + base);
  uint4 w = p4[threadIdx.x];                            // 256 uint4 = 1024 elems
  atomicAdd(&hist16[(w.x & UMASK) >> 15], 1u);
  atomicAdd(&hist16[(w.y & UMASK) >> 15], 1u);
  atomicAdd(&hist16[(w.z & UMASK) >> 15], 1u);
  atomicAdd(&hist16[(w.w & UMASK) >> 15], 1u);
}

// ---- Bounds: sample order stats sRank +/- MARGIN -> [lo, hi] band ----
__global__ void k_bounds(const uint32_t* __restrict__ hist16, uint32_t* meta,
                         uint32_t sRank) {
  __shared__ uint32_t part[NT];
  __shared__ uint32_t sLo, sHi;
  const int PER = HIST16_BINS / NT;  // 256
  int lo = threadIdx.x * PER;
  uint32_t s = 0;
  for (int b = 0; b < PER; ++b) s += hist16[lo + b];
  part[threadIdx.x] = s;
  __syncthreads();
  for (int off = 1; off < NT; off <<= 1) {
    uint32_t y = (threadIdx.x >= (unsigned)off) ? part[threadIdx.x - off] : 0u;
    __syncthreads();
    part[threadIdx.x] += y;
    __syncthreads();
  }
  uint32_t cum = part[threadIdx.x] - s;  // exclusive prefix of my chunk
  uint32_t loR = sRank - MARGIN, hiR = sRank + MARGIN;
  for (int b = 0; b < PER; ++b) {
    uint32_t h = hist16[lo + b];
    if (cum <= loR && loR < cum + h) sLo = (uint32_t)(lo + b) << 15;
    if (cum <= hiR && hiR < cum + h) sHi = (((uint32_t)(lo + b) + 1u) << 15) - 1u;
    cum += h;
  }
  __syncthreads();
  if (threadIdx.x == 0) {
    uint32_t l = sLo, h = sHi;
    meta[M_LO] = l;
    meta[M_HI] = h;
    meta[M_BASE7] = l >> 7;
    uint32_t span = (h >> 7) - (l >> 7) + 1u;
    if (span > HISTA_CAP) { span = HISTA_CAP; meta[M_FAIL] = 1u; }
    meta[M_SPANA] = span;
  }
}

// ---- THE full pass: provisional output + exact below-lo count + candidate
//      compaction into per-block regions + band histogram at (u>>7) ----
__global__ void k_scan(const uint32_t* __restrict__ param, long long n4,
                       uint32_t* meta, uint32_t* __restrict__ histA,
                       uint2* __restrict__ candBuf, uint32_t perBlockCap,
                       uint32_t* __restrict__ blockCounts,
                       float* __restrict__ out) {
  __shared__ uint32_t lcount;
  __shared__ uint32_t red[NT];
  if (threadIdx.x == 0) lcount = 0;
  __syncthreads();
  const uint32_t lo = meta[M_LO], hi = meta[M_HI], base7 = meta[M_BASE7];
  uint2* myRegion = candBuf + (size_t)blockIdx.x * perBlockCap;
  uint32_t nless = 0;
  const uint4* p4 = (const uint4*)param;
  float4* o4 = (float4*)out;
  long long stride = (long long)gridDim.x * NT;
  for (long long i = (long long)blockIdx.x * NT + threadIdx.x; i < n4; i += stride) {
    uint4 w = p4[i];
    uint32_t baseIdx = (uint32_t)(i << 2);
    uint32_t us[4] = { w.x & UMASK, w.y & UMASK, w.z & UMASK, w.w & UMASK };
    float4 r;
    float* rp = (float*)&r;
#pragma unroll
    for (int c = 0; c < 4; ++c) {
      uint32_t u = us[c];
      rp[c] = (u > hi) ? 1.0f : 0.0f;
      nless += (u < lo) ? 1u : 0u;
      if (u >= lo && u <= hi) {
        atomicAdd(&histA[(u >> 7) - base7], 1u);
        uint32_t p = atomicAdd(&lcount, 1u);
        if (p < perBlockCap) myRegion[p] = make_uint2(baseIdx + (uint32_t)c, u);
      }
    }
    o4[i] = r;
  }
  // block-reduce below-lo count
  red[threadIdx.x] = nless;
  __syncthreads();
  for (int off = NT / 2; off > 0; off >>= 1) {
    if (threadIdx.x < (unsigned)off) red[threadIdx.x] += red[threadIdx.x + off];
    __syncthreads();
  }
  if (threadIdx.x == 0) {
    atomicAdd(&meta[M_NLESSLO], red[0]);
    blockCounts[blockIdx.x] = lcount;
    if (lcount > perBlockCap) atomicOr(&meta[M_FAIL], 2u);
  }
}

// ---- Select the (u>>7) bin containing local rank ----
__global__ void k_selectA(const uint32_t* __restrict__ histA, uint32_t* meta,
                          uint32_t jrank) {
  __shared__ uint32_t part[NT];
  uint32_t span = meta[M_SPANA];
  uint32_t jl = jrank - meta[M_NLESSLO];
  uint32_t per = (span + NT - 1) / NT;
  uint32_t lo = threadIdx.x * per;
  uint32_t hiB = lo + per; if (hiB > span) hiB = span;
  uint32_t s = 0;
  for (uint32_t b = lo; b < hiB; ++b) s += histA[b];
  part[threadIdx.x] = s;
  __syncthreads();
  for (int off = 1; off < NT; off <<= 1) {
    uint32_t y = (threadIdx.x >= (unsigned)off) ? part[threadIdx.x - off] : 0u;
    __syncthreads();
    part[threadIdx.x] += y;
    __syncthreads();
  }
  uint32_t cum = part[threadIdx.x] - s;
  for (uint32_t b = lo; b < hiB; ++b) {
    uint32_t h = histA[b];
    if (cum <= jl && jl < cum + h) {
      meta[M_B7] = meta[M_BASE7] + b;
      meta[M_CUMA] = cum;
    }
    cum += h;
  }
}

// ---- Collect candidates in the selected (u>>7) bin ----
__global__ void k_collectB(const uint2* __restrict__ candBuf, uint32_t perBlockCap,
                           const uint32_t* __restrict__ blockCounts,
                           uint32_t* meta, uint2* __restrict__ b7buf) {
  uint32_t b7 = meta[M_B7];
  uint32_t cnt = blockCounts[blockIdx.x];
  if (cnt > perBlockCap) cnt = perBlockCap;
  const uint2* myRegion = candBuf + (size_t)blockIdx.x * perBlockCap;
  for (uint32_t i = threadIdx.x; i < cnt; i += NT) {
    uint2 e = myRegion[i];
    if ((e.y >> 7) == b7) {
      uint32_t p = atomicAdd(&meta[M_NB7], 1u);
      if (p < B7_CAP) b7buf[p] = e;
    }
  }
}

// ---- Final select within the bin: exact v + stable tie threshold I_thr ----
__global__ void k_selB(const uint2* __restrict__ b7buf, uint32_t* meta,
                       uint32_t jrank) {
  __shared__ uint32_t h[128];
  __shared__ uint32_t tieIdx[TIE_CAP];
  __shared__ uint32_t tcount;
  __shared__ uint32_t sv, sntz;
  uint32_t nb = meta[M_NB7]; if (nb > B7_CAP) nb = B7_CAP;
  if (threadIdx.x < 128) h[threadIdx.x] = 0;
  if (threadIdx.x == 0) { tcount = 0; sv = 0; sntz = 0; }
  __syncthreads();
  for (uint32_t i = threadIdx.x; i < nb; i += NT)
    atomicAdd(&h[b7buf[i].y & 127u], 1u);
  __syncthreads();
  if (threadIdx.x == 0) {
    uint32_t r = jrank - meta[M_NLESSLO] - meta[M_CUMA];
    uint32_t b7 = meta[M_B7];
    uint32_t cum = 0;
    for (int b = 0; b < 128; ++b) {
      uint32_t hv = h[b];
      if (cum <= r && r < cum + hv) {
        sv = (b7 << 7) | (uint32_t)b;
        sntz = r - cum;
        meta[M_V] = sv;
        break;
      }
      cum += hv;
    }
  }
  __syncthreads();
  uint32_t v = sv, ntz = sntz;
  for (uint32_t i = threadIdx.x; i < nb; i += NT) {
    uint2 e = b7buf[i];
    if (e.y == v) {
      uint32_t p = atomicAdd(&tcount, 1u);
      if (p < TIE_CAP) tieIdx[p] = e.x;
    }
  }
  __syncthreads();
  uint32_t T = tcount; if (T > TIE_CAP) T = TIE_CAP;
  if (ntz == 0) {
    if (threadIdx.x == 0) meta[M_ITHR] = 0u;  // all ties get 1
  } else {
    for (uint32_t t = threadIdx.x; t < T; t += NT) {
      uint32_t my = tieIdx[t], rk = 0;
      for (uint32_t s2 = 0; s2 < T; ++s2) rk += (tieIdx[s2] < my) ? 1u : 0u;
      if (rk == ntz) meta[M_ITHR] = my;  // stable: ntz lowest-index ties get 0
    }
  }
}

// ---- Fixup: rewrite exact value for every in-band element ----
__global__ void k_fixup(const uint2* __restrict__ candBuf, uint32_t perBlockCap,
                        const uint32_t* __restrict__ blockCounts,
                        const uint32_t* __restrict__ meta,
                        float* __restrict__ out) {
  uint32_t v = meta[M_V], it = meta[M_ITHR];
  uint32_t cnt = blockCounts[blockIdx.x];
  if (cnt > perBlockCap) cnt = perBlockCap;
  const uint2* myRegion = candBuf + (size_t)blockIdx.x * perBlockCap;
  for (uint32_t i = threadIdx.x; i < cnt; i += NT) {
    uint2 e = myRegion[i];
    out[e.x] = (e.y > v || (e.y == v && e.x >= it)) ? 1.0f : 0.0f;
  }
}

extern "C" void kernel_launch(void* const* d_in, const int* in_sizes, int n_in,
                              void* d_out, int out_size, void* d_ws, size_t ws_size,
                              hipStream_t stream) {
  const uint32_t* param = (const uint32_t*)d_in[0];
  float* out = (float*)d_out;
  long long n = (long long)in_sizes[0];   // 67108864, divisible by 4096
  long long n4 = n >> 2;
  uint32_t jrank = (uint32_t)(n / 2);     // int((1-0.5)*n)
  uint32_t sTotal = SAMPLE_BLOCKS * 1024u;
  uint32_t sRank = (uint32_t)(((unsigned long long)jrank * sTotal) / (unsigned long long)n);

  // workspace layout (u32 units)
  uint32_t* meta   = (uint32_t*)d_ws;              // 64
  uint32_t* hist16 = meta + 64;                    // 65536
  uint32_t* histA  = hist16 + HIST16_BINS;         // 16384
  const int nzero = 64 + HIST16_BINS + HISTA_CAP;  // 81984
  uint32_t* blockCounts = histA + HISTA_CAP;       // SCAN_BLOCKS
  uint2* b7buf = (uint2*)(blockCounts + SCAN_BLOCKS);          // B7_CAP uint2
  uint2* candBuf = b7buf + B7_CAP;
  size_t fixedBytes = (size_t)(nzero + SCAN_BLOCKS) * 4 + (size_t)B7_CAP * 8;

  uint32_t perBlockCap = 0;
  if (ws_size > fixedBytes + 8) {
    size_t slots = (ws_size - fixedBytes) / 8 / SCAN_BLOCKS;
    if (slots > 4096) slots = 4096;
    perBlockCap = (uint32_t)slots;
  }

  k_zero<<<(nzero + NT - 1) / NT, NT, 0, stream>>>(meta, nzero);
  k_sample<<<SAMPLE_BLOCKS, NT, 0, stream>>>(param, n, hist16);
  k_bounds<<<1, NT, 0, stream>>>(hist16, meta, sRank);
  k_scan<<<SCAN_BLOCKS, NT, 0, stream>>>(param, n4, meta, histA, candBuf,
                                         perBlockCap, blockCounts, out);
  k_selectA<<<1, NT, 0, stream>>>(histA, meta, jrank);
  k_collectB<<<SCAN_BLOCKS, NT, 0, stream>>>(candBuf, perBlockCap, blockCounts,
                                             meta, b7buf);
  k_selB<<<1, NT, 0, stream>>>(b7buf, meta, jrank);
  k_fixup<<<SCAN_BLOCKS, NT, 0, stream>>>(candBuf, perBlockCap, blockCounts,
                                          meta, out);
}

// Round 3
// 235.628 us; speedup vs baseline: 2.1270x; 2.1270x over previous
//
#include <hip/hip_runtime.h>
#include <stdint.h>

#define NT 256
#define SCAN_BLOCKS 2048
#define SAMPLE_BLOCKS 32
#define SAMPLE_PER_BLOCK 32768   // 32 * 32768 = 2^20 samples total
#define SBINS 16384              // sample hist bins: u >> 17  (64 KB LDS)
#define MARGIN 2500u
#define ABINS 4096               // band hist bins: u >> 8
#define CH_BLOCKS 64             // candidate-hist blocks
#define B8_CAP 8192
#define TIE_CAP 256
#define UMASK 0x7fffffffu

// meta slots (zeroed each launch)
enum {
  M_LO = 0,    // band lower bound (u-space, inclusive, bin-aligned)
  M_HI,        // band upper bound (inclusive)
  M_BASE8,     // lo >> 8
  M_SPANA,     // number of u>>8 bins in band
  M_NLESSLO,   // exact count of u < lo
  M_B8,        // selected u>>8 value (absolute)
  M_CUMA,      // candidates in bins < B8
  M_NB8,       // candidates with u>>8 == B8
  M_V,         // exact cutoff bit pattern
  M_ITHR,      // tie gets 1 iff idx >= I_thr
  M_FAIL,      // diagnostics
  M_NMETA
};

__global__ void k_zero(uint32_t* p, int n) {
  int i = blockIdx.x * NT + threadIdx.x;
  if (i < n) p[i] = 0;
}

// ---- sample 2^20 elements; per-block LDS hist; flush non-zero bins ----
__global__ void k_sample(const uint32_t* __restrict__ param, long long n,
                         uint32_t* __restrict__ hist16) {
  __shared__ uint32_t h[SBINS];  // 64 KB
  for (int i = threadIdx.x; i < SBINS; i += NT) h[i] = 0;
  __syncthreads();
  long long chunk = n / SAMPLE_BLOCKS;
  const uint4* p4 = (const uint4*)(param + (long long)blockIdx.x * chunk);
#pragma unroll 4
  for (int k = 0; k < SAMPLE_PER_BLOCK / 4; k += NT) {
    uint4 w = p4[k + threadIdx.x];
    atomicAdd(&h[(w.x & UMASK) >> 17], 1u);
    atomicAdd(&h[(w.y & UMASK) >> 17], 1u);
    atomicAdd(&h[(w.z & UMASK) >> 17], 1u);
    atomicAdd(&h[(w.w & UMASK) >> 17], 1u);
  }
  __syncthreads();
  for (int i = threadIdx.x; i < SBINS; i += NT) {
    uint32_t v = h[i];
    if (v) atomicAdd(&hist16[i], v);
  }
}

// ---- sample order stats sRank +/- MARGIN -> [lo, hi] band ----
__global__ void k_bounds(const uint32_t* __restrict__ hist16, uint32_t* meta,
                         uint32_t sRank) {
  __shared__ uint32_t part[NT];
  __shared__ uint32_t sLo, sHi;
  const int PER = SBINS / NT;  // 64
  int lo = threadIdx.x * PER;
  uint32_t s = 0;
  for (int b = 0; b < PER; ++b) s += hist16[lo + b];
  part[threadIdx.x] = s;
  __syncthreads();
  for (int off = 1; off < NT; off <<= 1) {
    uint32_t y = (threadIdx.x >= (unsigned)off) ? part[threadIdx.x - off] : 0u;
    __syncthreads();
    part[threadIdx.x] += y;
    __syncthreads();
  }
  uint32_t cum = part[threadIdx.x] - s;
  uint32_t loR = sRank - MARGIN, hiR = sRank + MARGIN;
  for (int b = 0; b < PER; ++b) {
    uint32_t hv = hist16[lo + b];
    if (cum <= loR && loR < cum + hv) sLo = (uint32_t)(lo + b) << 17;
    if (cum <= hiR && hiR < cum + hv) sHi = (((uint32_t)(lo + b) + 1u) << 17) - 1u;
    cum += hv;
  }
  __syncthreads();
  if (threadIdx.x == 0) {
    uint32_t l = sLo, hh = sHi;
    meta[M_LO] = l;
    meta[M_HI] = hh;
    meta[M_BASE8] = l >> 8;
    uint32_t span = (hh >> 8) - (l >> 8) + 1u;
    if (span > ABINS) { meta[M_FAIL] = 1u; span = ABINS; }
    meta[M_SPANA] = span;
  }
}

// ---- THE full pass: provisional output + exact below-lo count +
//      candidate compaction into per-block regions (NO global hist atomics) ----
__global__ void k_scan(const uint32_t* __restrict__ param, long long n4,
                       uint32_t* meta,
                       uint2* __restrict__ candBuf, uint32_t perBlockCap,
                       uint32_t* __restrict__ blockCounts,
                       float* __restrict__ out) {
  __shared__ uint32_t lcount;
  __shared__ uint32_t red[NT];
  if (threadIdx.x == 0) lcount = 0;
  __syncthreads();
  const uint32_t lo = meta[M_LO], hi = meta[M_HI];
  uint2* myRegion = candBuf + (size_t)blockIdx.x * perBlockCap;
  uint32_t nless = 0;
  const uint4* p4 = (const uint4*)param;
  float4* o4 = (float4*)out;
  long long stride = (long long)gridDim.x * NT;
  for (long long i = (long long)blockIdx.x * NT + threadIdx.x; i < n4; i += stride) {
    uint4 w = p4[i];
    uint32_t baseIdx = (uint32_t)(i << 2);
    uint32_t us[4] = { w.x & UMASK, w.y & UMASK, w.z & UMASK, w.w & UMASK };
    float4 r;
    float* rp = (float*)&r;
#pragma unroll
    for (int c = 0; c < 4; ++c) {
      uint32_t u = us[c];
      rp[c] = (u > hi) ? 1.0f : 0.0f;
      nless += (u < lo) ? 1u : 0u;
      if (u >= lo && u <= hi) {
        uint32_t p = atomicAdd(&lcount, 1u);
        if (p < perBlockCap) myRegion[p] = make_uint2(baseIdx + (uint32_t)c, u);
      }
    }
    o4[i] = r;
  }
  red[threadIdx.x] = nless;
  __syncthreads();
  for (int off = NT / 2; off > 0; off >>= 1) {
    if (threadIdx.x < (unsigned)off) red[threadIdx.x] += red[threadIdx.x + off];
    __syncthreads();
  }
  if (threadIdx.x == 0) {
    atomicAdd(&meta[M_NLESSLO], red[0]);
    blockCounts[blockIdx.x] = (lcount < perBlockCap) ? lcount : perBlockCap;
    if (lcount > perBlockCap) atomicOr(&meta[M_FAIL], 2u);
  }
}

// ---- candidate fine histogram (u>>8) into per-block private regions ----
__global__ void k_candhist(const uint2* __restrict__ candBuf, uint32_t perBlockCap,
                           const uint32_t* __restrict__ blockCounts,
                           const uint32_t* __restrict__ meta,
                           uint32_t* __restrict__ candHist) {
  __shared__ uint32_t h[ABINS];
  for (int i = threadIdx.x; i < ABINS; i += NT) h[i] = 0;
  __syncthreads();
  uint32_t base8 = meta[M_BASE8];
  const int RPG = SCAN_BLOCKS / CH_BLOCKS;  // 32
  for (int r = 0; r < RPG; ++r) {
    int reg = blockIdx.x * RPG + r;
    uint32_t cnt = blockCounts[reg];
    const uint2* myR = candBuf + (size_t)reg * perBlockCap;
    for (uint32_t i = threadIdx.x; i < cnt; i += NT) {
      uint32_t idx = (myR[i].y >> 8) - base8;
      if (idx >= ABINS) idx = ABINS - 1;  // defensive (M_FAIL path)
      atomicAdd(&h[idx], 1u);
    }
  }
  __syncthreads();
  uint32_t* outp = candHist + (size_t)blockIdx.x * ABINS;
  for (int i = threadIdx.x; i < ABINS; i += NT) outp[i] = h[i];
}

// ---- tree-reduce per-block hists -> histA ----
__global__ void k_reduceA(const uint32_t* __restrict__ candHist,
                          uint32_t* __restrict__ histA) {
  int b = blockIdx.x * NT + threadIdx.x;  // 16 blocks * 256 = 4096
  uint32_t s = 0;
#pragma unroll 8
  for (int g = 0; g < CH_BLOCKS; ++g) s += candHist[(size_t)g * ABINS + b];
  histA[b] = s;
}

// ---- select the u>>8 bin containing local rank ----
__global__ void k_selectA(const uint32_t* __restrict__ histA, uint32_t* meta,
                          uint32_t jrank) {
  __shared__ uint32_t part[NT];
  uint32_t jl = jrank - meta[M_NLESSLO];
  const int PER = ABINS / NT;  // 16
  int lo = threadIdx.x * PER;
  uint32_t s = 0;
  for (int b = 0; b < PER; ++b) s += histA[lo + b];
  part[threadIdx.x] = s;
  __syncthreads();
  for (int off = 1; off < NT; off <<= 1) {
    uint32_t y = (threadIdx.x >= (unsigned)off) ? part[threadIdx.x - off] : 0u;
    __syncthreads();
    part[threadIdx.x] += y;
    __syncthreads();
  }
  uint32_t cum = part[threadIdx.x] - s;
  for (int b = 0; b < PER; ++b) {
    uint32_t hv = histA[lo + b];
    if (cum <= jl && jl < cum + hv) {
      meta[M_B8] = meta[M_BASE8] + (uint32_t)(lo + b);
      meta[M_CUMA] = cum;
    }
    cum += hv;
  }
}

// ---- gather candidates in selected bin ----
__global__ void k_collectB(const uint2* __restrict__ candBuf, uint32_t perBlockCap,
                           const uint32_t* __restrict__ blockCounts,
                           uint32_t* meta, uint2* __restrict__ b8buf) {
  uint32_t b8 = meta[M_B8];
  uint32_t cnt = blockCounts[blockIdx.x];
  const uint2* myRegion = candBuf + (size_t)blockIdx.x * perBlockCap;
  for (uint32_t i = threadIdx.x; i < cnt; i += NT) {
    uint2 e = myRegion[i];
    if ((e.y >> 8) == b8) {
      uint32_t p = atomicAdd(&meta[M_NB8], 1u);
      if (p < B8_CAP) b8buf[p] = e;
    }
  }
}

// ---- exact cutoff v + stable tie threshold I_thr ----
__global__ void k_selB(const uint2* __restrict__ b8buf, uint32_t* meta,
                       uint32_t jrank) {
  __shared__ uint32_t h[256];
  __shared__ uint32_t tieIdx[TIE_CAP];
  __shared__ uint32_t tcount, sv, sntz;
  uint32_t nb = meta[M_NB8]; if (nb > B8_CAP) nb = B8_CAP;
  if (threadIdx.x < 256) h[threadIdx.x] = 0;
  if (threadIdx.x == 0) { tcount = 0; sv = 0; sntz = 0; }
  __syncthreads();
  for (uint32_t i = threadIdx.x; i < nb; i += NT)
    atomicAdd(&h[b8buf[i].y & 255u], 1u);
  __syncthreads();
  if (threadIdx.x == 0) {
    uint32_t r = jrank - meta[M_NLESSLO] - meta[M_CUMA];
    uint32_t b8 = meta[M_B8];
    uint32_t cum = 0;
    for (int b = 0; b < 256; ++b) {
      uint32_t hv = h[b];
      if (cum <= r && r < cum + hv) {
        sv = (b8 << 8) | (uint32_t)b;
        sntz = r - cum;
        meta[M_V] = sv;
        break;
      }
      cum += hv;
    }
  }
  __syncthreads();
  uint32_t v = sv, ntz = sntz;
  for (uint32_t i = threadIdx.x; i < nb; i += NT) {
    uint2 e = b8buf[i];
    if (e.y == v) {
      uint32_t p = atomicAdd(&tcount, 1u);
      if (p < TIE_CAP) tieIdx[p] = e.x;
    }
  }
  __syncthreads();
  uint32_t T = tcount; if (T > TIE_CAP) T = TIE_CAP;
  if (ntz == 0) {
    if (threadIdx.x == 0) meta[M_ITHR] = 0u;  // all ties get 1
  } else {
    for (uint32_t t = threadIdx.x; t < T; t += NT) {
      uint32_t my = tieIdx[t], rk = 0;
      for (uint32_t s2 = 0; s2 < T; ++s2) rk += (tieIdx[s2] < my) ? 1u : 0u;
      if (rk == ntz) meta[M_ITHR] = my;  // ntz lowest-index ties get 0
    }
  }
}

// ---- rewrite exact value for every in-band element ----
__global__ void k_fixup(const uint2* __restrict__ candBuf, uint32_t perBlockCap,
                        const uint32_t* __restrict__ blockCounts,
                        const uint32_t* __restrict__ meta,
                        float* __restrict__ out) {
  uint32_t v = meta[M_V], it = meta[M_ITHR];
  uint32_t cnt = blockCounts[blockIdx.x];
  const uint2* myRegion = candBuf + (size_t)blockIdx.x * perBlockCap;
  for (uint32_t i = threadIdx.x; i < cnt; i += NT) {
    uint2 e = myRegion[i];
    out[e.x] = (e.y > v || (e.y == v && e.x >= it)) ? 1.0f : 0.0f;
  }
}

extern "C" void kernel_launch(void* const* d_in, const int* in_sizes, int n_in,
                              void* d_out, int out_size, void* d_ws, size_t ws_size,
                              hipStream_t stream) {
  const uint32_t* param = (const uint32_t*)d_in[0];
  float* out = (float*)d_out;
  long long n = (long long)in_sizes[0];   // 67108864
  long long n4 = n >> 2;
  uint32_t jrank = (uint32_t)(n / 2);     // int((1-0.5)*n)
  unsigned long long sTotal = (unsigned long long)SAMPLE_BLOCKS * SAMPLE_PER_BLOCK;
  uint32_t sRank = (uint32_t)(((unsigned long long)jrank * sTotal) / (unsigned long long)n);

  // workspace layout (u32 units)
  uint32_t* meta     = (uint32_t*)d_ws;                         // 64
  uint32_t* hist16   = meta + 64;                               // SBINS
  uint32_t* candHist = hist16 + SBINS;                          // CH_BLOCKS*ABINS
  uint32_t* histA    = candHist + (size_t)CH_BLOCKS * ABINS;    // ABINS
  uint32_t* blockCounts = histA + ABINS;                        // SCAN_BLOCKS
  uint2* b8buf = (uint2*)(blockCounts + SCAN_BLOCKS);           // B8_CAP uint2
  uint2* candBuf = b8buf + B8_CAP;
  size_t fixedBytes = ((size_t)64 + SBINS + (size_t)CH_BLOCKS * ABINS + ABINS +
                       SCAN_BLOCKS) * 4 + (size_t)B8_CAP * 8;

  uint32_t perBlockCap = 0;
  if (ws_size > fixedBytes + 8) {
    size_t slots = (ws_size - fixedBytes) / 8 / SCAN_BLOCKS;
    if (slots > 4096) slots = 4096;
    perBlockCap = (uint32_t)slots;
  }

  const int nzero = 64 + SBINS;  // meta + sample hist
  k_zero<<<(nzero + NT - 1) / NT, NT, 0, stream>>>(meta, nzero);
  k_sample<<<SAMPLE_BLOCKS, NT, 0, stream>>>(param, n, hist16);
  k_bounds<<<1, NT, 0, stream>>>(hist16, meta, sRank);
  k_scan<<<SCAN_BLOCKS, NT, 0, stream>>>(param, n4, meta, candBuf, perBlockCap,
                                         blockCounts, out);
  k_candhist<<<CH_BLOCKS, NT, 0, stream>>>(candBuf, perBlockCap, blockCounts,
                                           meta, candHist);
  k_reduceA<<<ABINS / NT, NT, 0, stream>>>(candHist, histA);
  k_selectA<<<1, NT, 0, stream>>>(histA, meta, jrank);
  k_collectB<<<SCAN_BLOCKS, NT, 0, stream>>>(candBuf, perBlockCap, blockCounts,
                                             meta, b8buf);
  k_selB<<<1, NT, 0, stream>>>(b8buf, meta, jrank);
  k_fixup<<<SCAN_BLOCKS, NT, 0, stream>>>(candBuf, perBlockCap, blockCounts,
                                          meta, out);
}

// Round 4
// 235.211 us; speedup vs baseline: 2.1307x; 1.0018x over previous
//
#include <hip/hip_runtime.h>
#include <stdint.h>

#define NT 256
#define SCAN_BLOCKS 2048
#define SAMPLE_BLOCKS 64
#define SAMPLES_PER_BLOCK 16384   // 64 * 16384 = 2^20 samples
#define SBINS 16384               // sample hist bins: u >> 17 (64 KB LDS)
#define MARGIN 2500u
#define RBINS 256                 // candidate hist bins: (u>>11) - base11
#define REDUCE_BLOCKS 64
#define COLLECT_BLOCKS 256
#define LBUF_CAP 512
#define B8_CAP 8192
#define TIE_CAP 256
#define FBINS 2048                // final select: u & 2047 within the u>>11 bin
#define UMASK 0x7fffffffu

// meta slots (zeroed each launch)
enum {
  M_LO = 0,    // band lower bound (inclusive, 2^17-aligned)
  M_HI,        // band upper bound (inclusive)
  M_NB8,       // gathered bin-B candidate count
  M_BINB,      // selected relative u>>11 bin (same value written by all collect blocks)
  M_CUMA,      // candidates in bins < BINB
  M_NLESS,     // exact count of u < lo
  M_FAIL,      // diagnostics
  M_NMETA
};

__global__ void k_zero(uint32_t* p, int n) {
  int i = blockIdx.x * NT + threadIdx.x;
  if (i < n) p[i] = 0;
}

// ---- sample 2^20 elements; per-block 64KB LDS hist; flush non-zero bins ----
__global__ void k_sample(const uint32_t* __restrict__ param, long long n,
                         uint32_t* __restrict__ hist16) {
  __shared__ uint32_t h[SBINS];  // 64 KB
  for (int i = threadIdx.x; i < SBINS; i += NT) h[i] = 0;
  __syncthreads();
  long long chunk = n / SAMPLE_BLOCKS;
  const uint4* p4 = (const uint4*)(param + (long long)blockIdx.x * chunk);
#pragma unroll 4
  for (int k = 0; k < SAMPLES_PER_BLOCK / 4; k += NT) {
    uint4 w = p4[k + threadIdx.x];
    atomicAdd(&h[(w.x & UMASK) >> 17], 1u);
    atomicAdd(&h[(w.y & UMASK) >> 17], 1u);
    atomicAdd(&h[(w.z & UMASK) >> 17], 1u);
    atomicAdd(&h[(w.w & UMASK) >> 17], 1u);
  }
  __syncthreads();
  for (int i = threadIdx.x; i < SBINS; i += NT) {
    uint32_t v = h[i];
    if (v) atomicAdd(&hist16[i], v);
  }
}

// ---- sample order stats sRank +/- MARGIN -> [lo, hi] band ----
__global__ void k_bounds(const uint32_t* __restrict__ hist16, uint32_t* meta,
                         uint32_t sRank) {
  __shared__ uint32_t part[NT];
  __shared__ uint32_t sLo, sHi;
  const int PER = SBINS / NT;  // 64
  int lo = threadIdx.x * PER;
  uint32_t s = 0;
  for (int b = 0; b < PER; ++b) s += hist16[lo + b];
  part[threadIdx.x] = s;
  __syncthreads();
  for (int off = 1; off < NT; off <<= 1) {
    uint32_t y = (threadIdx.x >= (unsigned)off) ? part[threadIdx.x - off] : 0u;
    __syncthreads();
    part[threadIdx.x] += y;
    __syncthreads();
  }
  uint32_t cum = part[threadIdx.x] - s;
  uint32_t loR = sRank - MARGIN, hiR = sRank + MARGIN;
  for (int b = 0; b < PER; ++b) {
    uint32_t hv = hist16[lo + b];
    if (cum <= loR && loR < cum + hv) sLo = (uint32_t)(lo + b) << 17;
    if (cum <= hiR && hiR < cum + hv) sHi = (((uint32_t)(lo + b) + 1u) << 17) - 1u;
    cum += hv;
  }
  __syncthreads();
  if (threadIdx.x == 0) {
    meta[M_LO] = sLo;
    meta[M_HI] = sHi;
    if (((sHi >> 11) - (sLo >> 11) + 1u) > RBINS) meta[M_FAIL] = 1u;
  }
}

// ---- THE full pass: provisional output + per-block below-lo count +
//      candidate compaction into per-block regions ----
__global__ void k_scan(const uint32_t* __restrict__ param, long long n4,
                       const uint32_t* __restrict__ meta,
                       uint2* __restrict__ candBuf, uint32_t perBlockCap,
                       uint32_t* __restrict__ blockCounts,
                       uint32_t* __restrict__ blockNless,
                       float* __restrict__ out) {
  __shared__ uint32_t lcount;
  __shared__ uint32_t red[NT];
  if (threadIdx.x == 0) lcount = 0;
  __syncthreads();
  const uint32_t lo = meta[M_LO], hi = meta[M_HI];
  uint2* myRegion = candBuf + (size_t)blockIdx.x * perBlockCap;
  uint32_t nless = 0;
  const uint4* p4 = (const uint4*)param;
  float4* o4 = (float4*)out;
  long long stride = (long long)gridDim.x * NT;
  for (long long i = (long long)blockIdx.x * NT + threadIdx.x; i < n4; i += stride) {
    uint4 w = p4[i];
    uint32_t baseIdx = (uint32_t)(i << 2);
    uint32_t us[4] = { w.x & UMASK, w.y & UMASK, w.z & UMASK, w.w & UMASK };
    float4 r;
    float* rp = (float*)&r;
#pragma unroll
    for (int c = 0; c < 4; ++c) {
      uint32_t u = us[c];
      rp[c] = (u > hi) ? 1.0f : 0.0f;
      nless += (u < lo) ? 1u : 0u;
      if (u >= lo && u <= hi) {
        uint32_t p = atomicAdd(&lcount, 1u);
        if (p < perBlockCap) myRegion[p] = make_uint2(baseIdx + (uint32_t)c, u);
      }
    }
    o4[i] = r;
  }
  red[threadIdx.x] = nless;
  __syncthreads();
  for (int off = NT / 2; off > 0; off >>= 1) {
    if (threadIdx.x < (unsigned)off) red[threadIdx.x] += red[threadIdx.x + off];
    __syncthreads();
  }
  if (threadIdx.x == 0) {
    blockNless[blockIdx.x] = red[0];
    blockCounts[blockIdx.x] = (lcount < perBlockCap) ? lcount : perBlockCap;
  }
}

// ---- candidate hist (u>>11 rel) over 32 regions/block; transposed flush ----
__global__ void k_reduce(const uint2* __restrict__ candBuf, uint32_t perBlockCap,
                         const uint32_t* __restrict__ blockCounts,
                         const uint32_t* __restrict__ meta,
                         uint32_t* __restrict__ candHist2) {
  __shared__ uint32_t h[RBINS];
  for (int i = threadIdx.x; i < RBINS; i += NT) h[i] = 0;
  __syncthreads();
  uint32_t base11 = meta[M_LO] >> 11;
  const int RPG = SCAN_BLOCKS / REDUCE_BLOCKS;  // 32
  for (int r = 0; r < RPG; ++r) {
    int reg = blockIdx.x * RPG + r;
    uint32_t cnt = blockCounts[reg];
    const uint2* my = candBuf + (size_t)reg * perBlockCap;
    for (uint32_t i = threadIdx.x; i < cnt; i += NT) {
      uint32_t rel = (my[i].y >> 11) - base11;
      if (rel >= RBINS) rel = RBINS - 1;  // defensive
      atomicAdd(&h[rel], 1u);
    }
  }
  __syncthreads();
  for (int b = threadIdx.x; b < RBINS; b += NT)
    candHist2[(size_t)b * REDUCE_BLOCKS + blockIdx.x] = h[b];
}

// ---- each block: redundant reduce+select (deterministic), then gather binB ----
__global__ void k_collect(const uint2* __restrict__ candBuf, uint32_t perBlockCap,
                          const uint32_t* __restrict__ blockCounts,
                          const uint32_t* __restrict__ blockNless,
                          const uint32_t* __restrict__ candHist2,
                          uint32_t* meta, uint2* __restrict__ b8buf,
                          uint32_t jrank) {
  __shared__ uint32_t histA[RBINS];
  __shared__ uint32_t part[NT];
  __shared__ uint32_t sBin, sCum;
  __shared__ uint2 lbuf[LBUF_CAP];
  __shared__ uint32_t lcnt, base;
  // reduce candHist2: thread t owns bin t (contiguous 64-u32 row)
  {
    uint32_t s = 0;
    const uint32_t* row = candHist2 + (size_t)threadIdx.x * REDUCE_BLOCKS;
    for (int g = 0; g < REDUCE_BLOCKS; ++g) s += row[g];
    histA[threadIdx.x] = s;
  }
  // total below-lo count
  uint32_t ns = 0;
  for (int i = threadIdx.x; i < SCAN_BLOCKS; i += NT) ns += blockNless[i];
  part[threadIdx.x] = ns;
  __syncthreads();
  for (int off = NT / 2; off > 0; off >>= 1) {
    if (threadIdx.x < (unsigned)off) part[threadIdx.x] += part[threadIdx.x + off];
    __syncthreads();
  }
  uint32_t nless = part[0];
  __syncthreads();
  // prefix over histA
  uint32_t h = histA[threadIdx.x];
  part[threadIdx.x] = h;
  __syncthreads();
  for (int off = 1; off < NT; off <<= 1) {
    uint32_t y = (threadIdx.x >= (unsigned)off) ? part[threadIdx.x - off] : 0u;
    __syncthreads();
    part[threadIdx.x] += y;
    __syncthreads();
  }
  uint32_t jl = jrank - nless;
  uint32_t cum = part[threadIdx.x] - h;
  if (threadIdx.x == 0) lcnt = 0;
  if (cum <= jl && jl < cum + h) { sBin = threadIdx.x; sCum = cum; }
  __syncthreads();
  uint32_t binB = sBin;
  if (threadIdx.x == 0) {  // same value from every block: benign
    meta[M_BINB] = binB; meta[M_CUMA] = sCum; meta[M_NLESS] = nless;
  }
  uint32_t base11 = meta[M_LO] >> 11;
  const int RPG = SCAN_BLOCKS / COLLECT_BLOCKS;  // 8
  for (int r = 0; r < RPG; ++r) {
    int reg = blockIdx.x * RPG + r;
    uint32_t cnt = blockCounts[reg];
    const uint2* my = candBuf + (size_t)reg * perBlockCap;
    for (uint32_t i = threadIdx.x; i < cnt; i += NT) {
      uint2 e = my[i];
      if (((e.y >> 11) - base11) == binB) {
        uint32_t p = atomicAdd(&lcnt, 1u);
        if (p < LBUF_CAP) lbuf[p] = e;
      }
    }
  }
  __syncthreads();
  uint32_t c = (lcnt < LBUF_CAP) ? lcnt : LBUF_CAP;
  if (threadIdx.x == 0) base = atomicAdd(&meta[M_NB8], c);
  __syncthreads();
  for (uint32_t i = threadIdx.x; i < c; i += NT) {
    uint32_t p = base + i;
    if (p < B8_CAP) b8buf[p] = lbuf[i];
  }
}

// ---- each block: redundant exact select (v, stable tie threshold) from b8buf
//      (order-independent -> deterministic), then fix its region ----
__global__ void k_fixup(const uint2* __restrict__ candBuf, uint32_t perBlockCap,
                        const uint32_t* __restrict__ blockCounts,
                        const uint32_t* __restrict__ meta,
                        const uint2* __restrict__ b8buf,
                        float* __restrict__ out, uint32_t jrank) {
  __shared__ uint32_t h[FBINS];  // 8 KB
  __shared__ uint32_t part[NT];
  __shared__ uint32_t tie[TIE_CAP];
  __shared__ uint32_t tcnt, sV, sNtz, sIthr;
  for (int i = threadIdx.x; i < FBINS; i += NT) h[i] = 0;
  if (threadIdx.x == 0) { tcnt = 0; sIthr = 0; sNtz = 0; }
  __syncthreads();
  uint32_t nb = meta[M_NB8]; if (nb > B8_CAP) nb = B8_CAP;
  uint32_t vbase = ((meta[M_LO] >> 11) + meta[M_BINB]) << 11;
  for (uint32_t i = threadIdx.x; i < nb; i += NT)
    atomicAdd(&h[b8buf[i].y & (FBINS - 1)], 1u);
  __syncthreads();
  // prefix over FBINS: 8 bins/thread serial + block scan
  const int PER = FBINS / NT;  // 8
  uint32_t loB = threadIdx.x * PER, s = 0;
  for (int b = 0; b < PER; ++b) s += h[loB + b];
  part[threadIdx.x] = s;
  __syncthreads();
  for (int off = 1; off < NT; off <<= 1) {
    uint32_t y = (threadIdx.x >= (unsigned)off) ? part[threadIdx.x - off] : 0u;
    __syncthreads();
    part[threadIdx.x] += y;
    __syncthreads();
  }
  uint32_t jl2 = jrank - meta[M_NLESS] - meta[M_CUMA];
  uint32_t cum = part[threadIdx.x] - s;
  for (int b = 0; b < PER; ++b) {
    uint32_t hv = h[loB + b];
    if (cum <= jl2 && jl2 < cum + hv) { sV = vbase + loB + (uint32_t)b; sNtz = jl2 - cum; }
    cum += hv;
  }
  __syncthreads();
  uint32_t v = sV, ntz = sNtz;
  if (ntz) {
    for (uint32_t i = threadIdx.x; i < nb; i += NT) {
      uint2 e = b8buf[i];
      if (e.y == v) {
        uint32_t p = atomicAdd(&tcnt, 1u);
        if (p < TIE_CAP) tie[p] = e.x;
      }
    }
    __syncthreads();
    uint32_t T = (tcnt < TIE_CAP) ? tcnt : TIE_CAP;
    for (uint32_t t = threadIdx.x; t < T; t += NT) {
      uint32_t my = tie[t], rk = 0;
      for (uint32_t q = 0; q < T; ++q) rk += (tie[q] < my) ? 1u : 0u;
      if (rk == ntz) sIthr = my;  // ntz lowest-index ties get 0
    }
    __syncthreads();
  }
  uint32_t it = sIthr;
  uint32_t cnt = blockCounts[blockIdx.x];
  const uint2* my = candBuf + (size_t)blockIdx.x * perBlockCap;
  for (uint32_t i = threadIdx.x; i < cnt; i += NT) {
    uint2 e = my[i];
    out[e.x] = (e.y > v || (e.y == v && e.x >= it)) ? 1.0f : 0.0f;
  }
}

extern "C" void kernel_launch(void* const* d_in, const int* in_sizes, int n_in,
                              void* d_out, int out_size, void* d_ws, size_t ws_size,
                              hipStream_t stream) {
  const uint32_t* param = (const uint32_t*)d_in[0];
  float* out = (float*)d_out;
  long long n = (long long)in_sizes[0];   // 67108864
  long long n4 = n >> 2;
  uint32_t jrank = (uint32_t)(n / 2);
  unsigned long long sTotal = (unsigned long long)SAMPLE_BLOCKS * SAMPLES_PER_BLOCK;
  uint32_t sRank = (uint32_t)(((unsigned long long)jrank * sTotal) / (unsigned long long)n);

  // workspace layout (u32 units)
  uint32_t* meta      = (uint32_t*)d_ws;                        // 64
  uint32_t* hist16    = meta + 64;                              // SBINS
  uint32_t* candHist2 = hist16 + SBINS;                         // RBINS*REDUCE_BLOCKS
  uint32_t* blockCounts = candHist2 + RBINS * REDUCE_BLOCKS;    // SCAN_BLOCKS
  uint32_t* blockNless  = blockCounts + SCAN_BLOCKS;            // SCAN_BLOCKS
  uint2* b8buf = (uint2*)(blockNless + SCAN_BLOCKS);            // B8_CAP uint2
  uint2* candBuf = b8buf + B8_CAP;
  size_t fixedBytes = ((size_t)64 + SBINS + RBINS * REDUCE_BLOCKS +
                       2 * SCAN_BLOCKS) * 4 + (size_t)B8_CAP * 8;

  uint32_t perBlockCap = 0;
  if (ws_size > fixedBytes + 8) {
    size_t slots = (ws_size - fixedBytes) / 8 / SCAN_BLOCKS;
    if (slots > 4096) slots = 4096;
    perBlockCap = (uint32_t)slots;
  }

  const int nzero = 64 + SBINS + RBINS * REDUCE_BLOCKS;  // 32832
  k_zero<<<(nzero + NT - 1) / NT, NT, 0, stream>>>(meta, nzero);
  k_sample<<<SAMPLE_BLOCKS, NT, 0, stream>>>(param, n, hist16);
  k_bounds<<<1, NT, 0, stream>>>(hist16, meta, sRank);
  k_scan<<<SCAN_BLOCKS, NT, 0, stream>>>(param, n4, meta, candBuf, perBlockCap,
                                         blockCounts, blockNless, out);
  k_reduce<<<REDUCE_BLOCKS, NT, 0, stream>>>(candBuf, perBlockCap, blockCounts,
                                             meta, candHist2);
  k_collect<<<COLLECT_BLOCKS, NT, 0, stream>>>(candBuf, perBlockCap, blockCounts,
                                               blockNless, candHist2, meta,
                                               b8buf, jrank);
  k_fixup<<<SCAN_BLOCKS, NT, 0, stream>>>(candBuf, perBlockCap, blockCounts,
                                          meta, b8buf, out, jrank);
}